// Round 4
// baseline (462.748 us; speedup 1.0000x reference)
//
#include <hip/hip_runtime.h>

// Laplacian-kernel regression, fused flash-style, bf16 MFMA 16x16x32 w/ 4x4
// register blocking (m97 recipe: 8 ds_read_b128 per 16 MFMA = 0.031 B/FLOP).
//   d2 = ||x||^2 + ||z||^2 - 2 X.Z^T ; P = exp(-sqrt(d2)/10) ; out = P @ W
// 256 thr / 4 waves; BM=128 x BN=128 S-tile (2x2 wave quadrants, 64 S-regs);
// PV: O = 128x256, wave = 64x128 (128 O-regs). Grid 512 = 64 row-tiles x 8
// M-chunks (chunk = bid&7 == XCD for L2 residency); atomicAdd combine.
// LDS: sW aliases sX+sZ (phase-disjoint); 72.7 KB -> 2 blocks/CU.

using frag8 = __attribute__((ext_vector_type(8))) short;   // 8 bf16 (4 VGPRs)
using f32x4 = __attribute__((ext_vector_type(4))) float;   // 16x16 C/D frag

constexpr int Nn = 8192, Mm = 8192, Dd = 512, Yd = 256;
constexpr int BM = 128, BN = 128, BK = 64;
constexpr int MCH = 8, MPER = Mm / MCH, MT = MPER / BN;    // 8 chunks, 8 tiles each
constexpr int LDX = BK + 8;    // 72
constexpr int LDP = BN + 8;    // 136
constexpr int LDW = 64 + 8;    // 72

// workspace layout (bytes)
constexpr size_t OFF_XB  = 0;
constexpr size_t OFF_ZB  = OFF_XB + (size_t)Nn * Dd * 2;
constexpr size_t OFF_WT  = OFF_ZB + (size_t)Mm * Dd * 2;
constexpr size_t OFF_XSQ = OFF_WT + (size_t)Yd * Mm * 2;
constexpr size_t OFF_ZSQ = OFF_XSQ + (size_t)Nn * 4;
constexpr size_t WS_NEED = OFF_ZSQ + (size_t)Mm * 4;       // ~21 MB

__device__ __forceinline__ ushort f2bf(float f) {
    unsigned u = __builtin_bit_cast(unsigned, f);
    u += 0x7FFFu + ((u >> 16) & 1u);
    return (ushort)(u >> 16);
}

// ---- prep 1: bf16 cast + row norms for X and Z in one launch ----
__global__ __launch_bounds__(256) void cast_norm_xz(
    const float* __restrict__ X, const float* __restrict__ Z,
    ushort* __restrict__ Xb, ushort* __restrict__ Zb,
    float* __restrict__ xsq, float* __restrict__ zsq) {
    const int wid = threadIdx.x >> 6, lane = threadIdx.x & 63;
    int row = blockIdx.x * 4 + wid;
    const float* src; ushort* dst; float* nrm;
    if (row < Nn) { src = X; dst = Xb; nrm = xsq; }
    else { row -= Nn; src = Z; dst = Zb; nrm = zsq; }
    const float* s = src + (size_t)row * Dd + lane * 8;
    const float4 a = ((const float4*)s)[0];
    const float4 b = ((const float4*)s)[1];
    uint4 pk;
    pk.x = (unsigned)f2bf(a.x) | ((unsigned)f2bf(a.y) << 16);
    pk.y = (unsigned)f2bf(a.z) | ((unsigned)f2bf(a.w) << 16);
    pk.z = (unsigned)f2bf(b.x) | ((unsigned)f2bf(b.y) << 16);
    pk.w = (unsigned)f2bf(b.z) | ((unsigned)f2bf(b.w) << 16);
    *(uint4*)(dst + (size_t)row * Dd + lane * 8) = pk;
    float sq = a.x*a.x + a.y*a.y + a.z*a.z + a.w*a.w
             + b.x*b.x + b.y*b.y + b.z*b.z + b.w*b.w;
    #pragma unroll
    for (int off = 32; off; off >>= 1) sq += __shfl_xor(sq, off);
    if (lane == 0) nrm[row] = sq;
}

// ---- prep 2: W[8192][256] fp32 -> Wt[256][8192] bf16 ----
__global__ __launch_bounds__(256) void transpose_w(const float* __restrict__ Wf,
                                                   ushort* __restrict__ Wt) {
    __shared__ float tile[64][65];
    const int m0 = blockIdx.x * 64, n0 = blockIdx.y * 64;
    const int t = threadIdx.x;
    #pragma unroll
    for (int rep = 0; rep < 4; ++rep) {
        const int r = rep * 16 + (t >> 4), c4 = (t & 15) * 4;
        const float4 v = *(const float4*)(Wf + (size_t)(m0 + r) * Yd + n0 + c4);
        tile[r][c4] = v.x; tile[r][c4+1] = v.y; tile[r][c4+2] = v.z; tile[r][c4+3] = v.w;
    }
    __syncthreads();
    #pragma unroll
    for (int rep = 0; rep < 4; ++rep) {
        const int n = rep * 16 + (t >> 4), m4 = (t & 15) * 4;
        ushort4 pk;
        pk.x = f2bf(tile[m4+0][n]); pk.y = f2bf(tile[m4+1][n]);
        pk.z = f2bf(tile[m4+2][n]); pk.w = f2bf(tile[m4+3][n]);
        *(ushort4*)(Wt + (size_t)(n0 + n) * Mm + m0 + m4) = pk;
    }
}

// ---- main fused kernel ----
__global__ __launch_bounds__(256, 2) void laplace_mfma16(
    const ushort* __restrict__ Xb, const ushort* __restrict__ Zb,
    const ushort* __restrict__ Wt, const float* __restrict__ xsqg,
    const float* __restrict__ zsqg, float* __restrict__ O)
{
    // [0,36864) = sX(18432)+sZ(18432), aliased by sW(36864) in PV phase;
    // [36864,71680) = sP; [71680,72704) = norms
    __shared__ __align__(16) char smem[72704];
    ushort* sX = (ushort*)smem;
    ushort* sZ = sX + BM * LDX;
    ushort* sW = (ushort*)smem;
    ushort* sP = (ushort*)(smem + 36864);
    float* sXsq = (float*)(smem + 71680);
    float* sZsq = sXsq + 128;

    const int t = threadIdx.x;
    const int wid = t >> 6, lane = t & 63;
    const int l16 = lane & 15, quad = lane >> 4;
    const int wx = wid >> 1, wz = wid & 1;      // QK quadrant
    const int px = wid >> 1, py = wid & 1;      // PV: x-half, y-half
    const int bid = blockIdx.x;
    const int row0  = (bid >> 3) * BM;          // 64 row tiles
    const int zbase = (bid & 7) * MPER;         // chunk == XCD (round-robin)

    if (t < 128) sXsq[t] = xsqg[row0 + t];

    f32x4 Oa[4][8];                              // 64x128 per wave, 128 VGPRs
    #pragma unroll
    for (int i = 0; i < 4; ++i)
        #pragma unroll
        for (int j = 0; j < 8; ++j)
            #pragma unroll
            for (int r = 0; r < 4; ++r) Oa[i][j][r] = 0.0f;

    for (int mt = 0; mt < MT; ++mt) {
        const int zrow0 = zbase + mt * BN;
        if (t < 128) sZsq[t] = zsqg[zrow0 + t];  // visible via kk=0 barriers

        f32x4 S[4][4];                            // 64x64 per wave, 64 VGPRs
        #pragma unroll
        for (int i = 0; i < 4; ++i)
            #pragma unroll
            for (int j = 0; j < 4; ++j)
                #pragma unroll
                for (int r = 0; r < 4; ++r) S[i][j][r] = 0.0f;

        // ---- QK: S = X_tile . Z_tile^T, 8 slabs of K=64 ----
        for (int kk = 0; kk < Dd / BK; ++kk) {
            __syncthreads();   // prev consumers done (MFMA reads / sW reads)
            const ushort* xsrc = Xb + (size_t)row0 * Dd + kk * BK;
            const ushort* zsrc = Zb + (size_t)zrow0 * Dd + kk * BK;
            #pragma unroll
            for (int rep = 0; rep < 4; ++rep) {
                const int idx = rep * 256 + t;
                const int r = idx >> 3, c = idx & 7;
                *(uint4*)(sX + r * LDX + c * 8) =
                    *(const uint4*)(xsrc + (size_t)r * Dd + c * 8);
                *(uint4*)(sZ + r * LDX + c * 8) =
                    *(const uint4*)(zsrc + (size_t)r * Dd + c * 8);
            }
            __syncthreads();
            #pragma unroll
            for (int ks = 0; ks < 2; ++ks) {
                const int kof = ks * 32 + quad * 8;
                frag8 a[4], b[4];
                #pragma unroll
                for (int i = 0; i < 4; ++i)
                    a[i] = *(const frag8*)(sX + (wx * 64 + 16 * i + l16) * LDX + kof);
                #pragma unroll
                for (int j = 0; j < 4; ++j)
                    b[j] = *(const frag8*)(sZ + (wz * 64 + 16 * j + l16) * LDX + kof);
                #pragma unroll
                for (int i = 0; i < 4; ++i)
                    #pragma unroll
                    for (int j = 0; j < 4; ++j)
                        S[i][j] = __builtin_amdgcn_mfma_f32_16x16x32_bf16(
                            a[i], b[j], S[i][j], 0, 0, 0);
            }
        }

        // ---- transform -> sP[x][z] bf16 (C/D: col=l16, row=quad*4+reg) ----
        #pragma unroll
        for (int i = 0; i < 4; ++i) {
            const int xl = wx * 64 + 16 * i + quad * 4;
            #pragma unroll
            for (int j = 0; j < 4; ++j) {
                const int col = wz * 64 + 16 * j + l16;
                const float zs = sZsq[col];
                #pragma unroll
                for (int r = 0; r < 4; ++r) {
                    const float d2 = fmaxf(sXsq[xl + r] + zs - 2.0f * S[i][j][r], 0.0f);
                    sP[(xl + r) * LDP + col] = f2bf(__expf(-0.1f * __builtin_sqrtf(d2)));
                }
            }
        }
        __syncthreads();   // sP visible; sX/sZ reads done -> sW may overwrite

        // ---- PV: O += P[128x128] . W[128x256], z in two halves of 64 ----
        #pragma unroll
        for (int h = 0; h < 2; ++h) {
            #pragma unroll
            for (int rep = 0; rep < 8; ++rep) {   // 256 rows x 64 k = 2048 uint4
                const int idx = rep * 256 + t;
                const int n = idx >> 3, c = idx & 7;
                *(uint4*)(sW + n * LDW + c * 8) =
                    *(const uint4*)(Wt + (size_t)n * Mm + zrow0 + h * 64 + c * 8);
            }
            __syncthreads();
            #pragma unroll
            for (int kb = 0; kb < 2; ++kb) {
                const int kof = kb * 32 + quad * 8;
                frag8 ap[4];
                #pragma unroll
                for (int i = 0; i < 4; ++i)
                    ap[i] = *(const frag8*)(
                        sP + (px * 64 + 16 * i + l16) * LDP + h * 64 + kof);
                #pragma unroll
                for (int j = 0; j < 8; ++j) {
                    const frag8 bw = *(const frag8*)(
                        sW + (py * 128 + 16 * j + l16) * LDW + kof);
                    #pragma unroll
                    for (int i = 0; i < 4; ++i)
                        Oa[i][j] = __builtin_amdgcn_mfma_f32_16x16x32_bf16(
                            ap[i], bw, Oa[i][j], 0, 0, 0);
                }
            }
            __syncthreads();   // sW reads done before restage / next-mt staging
        }
    }

    // ---- epilogue: combine 8 M-chunks via fp32 atomics ----
    #pragma unroll
    for (int i = 0; i < 4; ++i) {
        const int xr = row0 + px * 64 + 16 * i + quad * 4;
        #pragma unroll
        for (int j = 0; j < 8; ++j) {
            const int col = py * 128 + 16 * j + l16;
            #pragma unroll
            for (int r = 0; r < 4; ++r)
                atomicAdd(&O[(size_t)(xr + r) * Yd + col], Oa[i][j][r]);
        }
    }
}

// ---- fallback (round-1 fp32 kernel) if workspace is too small ----
constexpr int FBM = 64, FBN = 64, FBK = 64;
constexpr int FMCH = 4, FMCHUNK = Mm / FMCH, FMSTEPS = FMCHUNK / FBN, FDSTEPS = Dd / FBK;
constexpr int FLDA = FBK + 1, FLDSS = FBN + 1;

__global__ __launch_bounds__(256, 3) void laplace_fused_v1(
    const float* __restrict__ X, const float* __restrict__ Z,
    const float* __restrict__ W, float* __restrict__ O)
{
    __shared__ float sX[FBM * FLDA];
    __shared__ float sZ[FBN * FLDA];
    __shared__ float sS[FBM * FLDSS];
    const int t = threadIdx.x, pr = t >> 4, pc = t & 15, sc4 = pc * 4;
    const int row0 = blockIdx.x * FBM, mbase = blockIdx.y * FMCHUNK;
    float o[4][4][4];
    #pragma unroll
    for (int i = 0; i < 4; ++i)
        for (int yb = 0; yb < 4; ++yb)
            for (int j = 0; j < 4; ++j) o[i][yb][j] = 0.0f;
    for (int ms = 0; ms < FMSTEPS; ++ms) {
        const int zrow0 = mbase + ms * FBN;
        float s[4][4];
        #pragma unroll
        for (int i = 0; i < 4; ++i)
            for (int j = 0; j < 4; ++j) s[i][j] = 0.0f;
        for (int kk = 0; kk < FDSTEPS; ++kk) {
            const int k0 = kk * FBK;
            __syncthreads();
            #pragma unroll
            for (int rep = 0; rep < 4; ++rep) {
                const int r = pr + rep * 16;
                const float4 xv = *reinterpret_cast<const float4*>(X + (size_t)(row0 + r) * Dd + k0 + sc4);
                const float4 zv = *reinterpret_cast<const float4*>(Z + (size_t)(zrow0 + r) * Dd + k0 + sc4);
                float* dx = sX + r * FLDA + sc4;
                dx[0] = xv.x; dx[1] = xv.y; dx[2] = xv.z; dx[3] = xv.w;
                float* dz = sZ + r * FLDA + sc4;
                dz[0] = zv.x; dz[1] = zv.y; dz[2] = zv.z; dz[3] = zv.w;
            }
            __syncthreads();
            #pragma unroll 4
            for (int k = 0; k < FBK; ++k) {
                float xr[4], zc[4];
                #pragma unroll
                for (int i = 0; i < 4; ++i) xr[i] = sX[(pr * 4 + i) * FLDA + k];
                #pragma unroll
                for (int j = 0; j < 4; ++j) zc[j] = sZ[(pc * 4 + j) * FLDA + k];
                #pragma unroll
                for (int i = 0; i < 4; ++i)
                    #pragma unroll
                    for (int j = 0; j < 4; ++j) {
                        const float d = xr[i] - zc[j];
                        s[i][j] = fmaf(d, d, s[i][j]);
                    }
            }
        }
        #pragma unroll
        for (int i = 0; i < 4; ++i)
            for (int j = 0; j < 4; ++j)
                sS[(pr * 4 + i) * FLDSS + sc4 + j] = __expf(-sqrtf(s[i][j]) * 0.1f);
        __syncthreads();
        #pragma unroll 2
        for (int c = 0; c < FBN; ++c) {
            float sv[4];
            #pragma unroll
            for (int i = 0; i < 4; ++i) sv[i] = sS[(pr * 4 + i) * FLDSS + c];
            const float* wrow = W + (size_t)(zrow0 + c) * Yd;
            #pragma unroll
            for (int yb = 0; yb < 4; ++yb) {
                const float4 wv = *reinterpret_cast<const float4*>(wrow + yb * 64 + sc4);
                #pragma unroll
                for (int i = 0; i < 4; ++i) {
                    o[i][yb][0] = fmaf(sv[i], wv.x, o[i][yb][0]);
                    o[i][yb][1] = fmaf(sv[i], wv.y, o[i][yb][1]);
                    o[i][yb][2] = fmaf(sv[i], wv.z, o[i][yb][2]);
                    o[i][yb][3] = fmaf(sv[i], wv.w, o[i][yb][3]);
                }
            }
        }
        __syncthreads();
    }
    #pragma unroll
    for (int i = 0; i < 4; ++i) {
        const size_t rbase = (size_t)(row0 + pr * 4 + i) * Yd;
        #pragma unroll
        for (int yb = 0; yb < 4; ++yb)
            for (int j = 0; j < 4; ++j)
                atomicAdd(O + rbase + yb * 64 + sc4 + j, o[i][yb][j]);
    }
}

extern "C" void kernel_launch(void* const* d_in, const int* in_sizes, int n_in,
                              void* d_out, int out_size, void* d_ws, size_t ws_size,
                              hipStream_t stream) {
    const float* X = (const float*)d_in[0];
    const float* Z = (const float*)d_in[1];
    const float* W = (const float*)d_in[2];
    float* O = (float*)d_out;

    hipMemsetAsync(d_out, 0, (size_t)out_size * sizeof(float), stream);

    if (ws_size < WS_NEED) {
        dim3 grid(Nn / FBM, FMCH);
        laplace_fused_v1<<<grid, dim3(256), 0, stream>>>(X, Z, W, O);
        return;
    }

    char* ws = (char*)d_ws;
    ushort* Xb  = (ushort*)(ws + OFF_XB);
    ushort* Zb  = (ushort*)(ws + OFF_ZB);
    ushort* Wt  = (ushort*)(ws + OFF_WT);
    float*  xsq = (float*)(ws + OFF_XSQ);
    float*  zsq = (float*)(ws + OFF_ZSQ);

    cast_norm_xz<<<dim3((Nn + Mm) / 4), dim3(256), 0, stream>>>(X, Z, Xb, Zb, xsq, zsq);
    transpose_w<<<dim3(Mm / 64, Yd / 64), dim3(256), 0, stream>>>(W, Wt);

    laplace_mfma16<<<dim3((Nn / BM) * MCH), dim3(256), 0, stream>>>(
        Xb, Zb, Wt, xsq, zsq, O);
}

// Round 5
// 451.147 us; speedup vs baseline: 1.0257x; 1.0257x over previous
//
#include <hip/hip_runtime.h>

// Laplacian-kernel regression, fused flash-style, bf16 MFMA 16x16x32 w/ 4x4
// register blocking.
//   d2 = ||x||^2 + ||z||^2 - 2 X.Z^T ; P = exp(-sqrt(d2)/10) ; out = P @ W
// 256 thr / 4 waves; BM=128 x BN=128 S-tile (2x2 wave quadrants); PV wave =
// 64x128 of O. Grid (64 row-tiles, 8 chunks) 2D: XCD = x%8 -> per-XCD X
// working set 1 MB (L2-resident), chunk writers of a row share an XCD (no
// cross-XCD atomic ping-pong). R4's chunk-major mapping thrashed L2
// (FETCH 526 MB); this restores R3 locality with R4's compute structure.
// LDS: sW aliases sX+sZ (phase-disjoint); 72.7 KB -> 2 blocks/CU.

using frag8 = __attribute__((ext_vector_type(8))) short;   // 8 bf16 (4 VGPRs)
using f32x4 = __attribute__((ext_vector_type(4))) float;   // 16x16 C/D frag

constexpr int Nn = 8192, Mm = 8192, Dd = 512, Yd = 256;
constexpr int BM = 128, BN = 128, BK = 64;
constexpr int MCH = 8, MPER = Mm / MCH, MT = MPER / BN;    // 8 chunks, 8 tiles each
constexpr int LDX = BK + 8;    // 72
constexpr int LDP = BN + 8;    // 136
constexpr int LDW = 64 + 8;    // 72

// workspace layout (bytes)
constexpr size_t OFF_XB  = 0;
constexpr size_t OFF_ZB  = OFF_XB + (size_t)Nn * Dd * 2;
constexpr size_t OFF_WT  = OFF_ZB + (size_t)Mm * Dd * 2;
constexpr size_t OFF_XSQ = OFF_WT + (size_t)Yd * Mm * 2;
constexpr size_t OFF_ZSQ = OFF_XSQ + (size_t)Nn * 4;
constexpr size_t WS_NEED = OFF_ZSQ + (size_t)Mm * 4;       // ~21 MB

__device__ __forceinline__ ushort f2bf(float f) {
    unsigned u = __builtin_bit_cast(unsigned, f);
    u += 0x7FFFu + ((u >> 16) & 1u);
    return (ushort)(u >> 16);
}

// ---- prep 1: bf16 cast + row norms for X and Z in one launch ----
__global__ __launch_bounds__(256) void cast_norm_xz(
    const float* __restrict__ X, const float* __restrict__ Z,
    ushort* __restrict__ Xb, ushort* __restrict__ Zb,
    float* __restrict__ xsq, float* __restrict__ zsq) {
    const int wid = threadIdx.x >> 6, lane = threadIdx.x & 63;
    int row = blockIdx.x * 4 + wid;
    const float* src; ushort* dst; float* nrm;
    if (row < Nn) { src = X; dst = Xb; nrm = xsq; }
    else { row -= Nn; src = Z; dst = Zb; nrm = zsq; }
    const float* s = src + (size_t)row * Dd + lane * 8;
    const float4 a = ((const float4*)s)[0];
    const float4 b = ((const float4*)s)[1];
    uint4 pk;
    pk.x = (unsigned)f2bf(a.x) | ((unsigned)f2bf(a.y) << 16);
    pk.y = (unsigned)f2bf(a.z) | ((unsigned)f2bf(a.w) << 16);
    pk.z = (unsigned)f2bf(b.x) | ((unsigned)f2bf(b.y) << 16);
    pk.w = (unsigned)f2bf(b.z) | ((unsigned)f2bf(b.w) << 16);
    *(uint4*)(dst + (size_t)row * Dd + lane * 8) = pk;
    float sq = a.x*a.x + a.y*a.y + a.z*a.z + a.w*a.w
             + b.x*b.x + b.y*b.y + b.z*b.z + b.w*b.w;
    #pragma unroll
    for (int off = 32; off; off >>= 1) sq += __shfl_xor(sq, off);
    if (lane == 0) nrm[row] = sq;
}

// ---- prep 2: W[8192][256] fp32 -> Wt[256][8192] bf16 ----
__global__ __launch_bounds__(256) void transpose_w(const float* __restrict__ Wf,
                                                   ushort* __restrict__ Wt) {
    __shared__ float tile[64][65];
    const int m0 = blockIdx.x * 64, n0 = blockIdx.y * 64;
    const int t = threadIdx.x;
    #pragma unroll
    for (int rep = 0; rep < 4; ++rep) {
        const int r = rep * 16 + (t >> 4), c4 = (t & 15) * 4;
        const float4 v = *(const float4*)(Wf + (size_t)(m0 + r) * Yd + n0 + c4);
        tile[r][c4] = v.x; tile[r][c4+1] = v.y; tile[r][c4+2] = v.z; tile[r][c4+3] = v.w;
    }
    __syncthreads();
    #pragma unroll
    for (int rep = 0; rep < 4; ++rep) {
        const int n = rep * 16 + (t >> 4), m4 = (t & 15) * 4;
        ushort4 pk;
        pk.x = f2bf(tile[m4+0][n]); pk.y = f2bf(tile[m4+1][n]);
        pk.z = f2bf(tile[m4+2][n]); pk.w = f2bf(tile[m4+3][n]);
        *(ushort4*)(Wt + (size_t)(n0 + n) * Mm + m0 + m4) = pk;
    }
}

// ---- main fused kernel ----
__global__ __launch_bounds__(256, 2) void laplace_mfma16(
    const ushort* __restrict__ Xb, const ushort* __restrict__ Zb,
    const ushort* __restrict__ Wt, const float* __restrict__ xsqg,
    const float* __restrict__ zsqg, float* __restrict__ O)
{
    // [0,36864) = sX(18432)+sZ(18432), aliased by sW(36864) in PV phase;
    // [36864,71680) = sP; [71680,72704) = norms
    __shared__ __align__(16) char smem[72704];
    ushort* sX = (ushort*)smem;
    ushort* sZ = sX + BM * LDX;
    ushort* sW = (ushort*)smem;
    ushort* sP = (ushort*)(smem + 36864);
    float* sXsq = (float*)(smem + 71680);
    float* sZsq = sXsq + 128;

    const int t = threadIdx.x;
    const int wid = t >> 6, lane = t & 63;
    const int l16 = lane & 15, quad = lane >> 4;
    const int wx = wid >> 1, wz = wid & 1;      // QK quadrant
    const int px = wid >> 1, py = wid & 1;      // PV: x-half, y-half
    const int row0  = blockIdx.x * BM;          // XCD = blockIdx.x % 8
    const int zbase = blockIdx.y * MPER;        // all chunks of a row: same XCD

    if (t < 128) sXsq[t] = xsqg[row0 + t];

    f32x4 Oa[4][8];                              // 64x128 per wave, 128 VGPRs
    #pragma unroll
    for (int i = 0; i < 4; ++i)
        #pragma unroll
        for (int j = 0; j < 8; ++j)
            #pragma unroll
            for (int r = 0; r < 4; ++r) Oa[i][j][r] = 0.0f;

    for (int mt = 0; mt < MT; ++mt) {
        const int zrow0 = zbase + mt * BN;
        if (t < 128) sZsq[t] = zsqg[zrow0 + t];  // visible via kk=0 barriers

        f32x4 S[4][4];                            // 64x64 per wave, 64 VGPRs
        #pragma unroll
        for (int i = 0; i < 4; ++i)
            #pragma unroll
            for (int j = 0; j < 4; ++j)
                #pragma unroll
                for (int r = 0; r < 4; ++r) S[i][j][r] = 0.0f;

        // ---- QK: S = X_tile . Z_tile^T, 8 slabs of K=64 ----
        for (int kk = 0; kk < Dd / BK; ++kk) {
            __syncthreads();   // prev consumers done (MFMA reads / sW reads)
            const ushort* xsrc = Xb + (size_t)row0 * Dd + kk * BK;
            const ushort* zsrc = Zb + (size_t)zrow0 * Dd + kk * BK;
            #pragma unroll
            for (int rep = 0; rep < 4; ++rep) {
                const int idx = rep * 256 + t;
                const int r = idx >> 3, c = idx & 7;
                *(uint4*)(sX + r * LDX + c * 8) =
                    *(const uint4*)(xsrc + (size_t)r * Dd + c * 8);
                *(uint4*)(sZ + r * LDX + c * 8) =
                    *(const uint4*)(zsrc + (size_t)r * Dd + c * 8);
            }
            __syncthreads();
            #pragma unroll
            for (int ks = 0; ks < 2; ++ks) {
                const int kof = ks * 32 + quad * 8;
                frag8 a[4], b[4];
                #pragma unroll
                for (int i = 0; i < 4; ++i)
                    a[i] = *(const frag8*)(sX + (wx * 64 + 16 * i + l16) * LDX + kof);
                #pragma unroll
                for (int j = 0; j < 4; ++j)
                    b[j] = *(const frag8*)(sZ + (wz * 64 + 16 * j + l16) * LDX + kof);
                #pragma unroll
                for (int i = 0; i < 4; ++i)
                    #pragma unroll
                    for (int j = 0; j < 4; ++j)
                        S[i][j] = __builtin_amdgcn_mfma_f32_16x16x32_bf16(
                            a[i], b[j], S[i][j], 0, 0, 0);
            }
        }

        // ---- transform -> sP[x][z] bf16 (C/D: col=l16, row=quad*4+reg) ----
        #pragma unroll
        for (int i = 0; i < 4; ++i) {
            const int xl = wx * 64 + 16 * i + quad * 4;
            #pragma unroll
            for (int j = 0; j < 4; ++j) {
                const int col = wz * 64 + 16 * j + l16;
                const float zs = sZsq[col];
                #pragma unroll
                for (int r = 0; r < 4; ++r) {
                    const float d2 = fmaxf(sXsq[xl + r] + zs - 2.0f * S[i][j][r], 0.0f);
                    sP[(xl + r) * LDP + col] = f2bf(__expf(-0.1f * __builtin_sqrtf(d2)));
                }
            }
        }
        __syncthreads();   // sP visible; sX/sZ reads done -> sW may overwrite

        // ---- PV: O += P[128x128] . W[128x256], z in two halves of 64 ----
        #pragma unroll
        for (int h = 0; h < 2; ++h) {
            #pragma unroll
            for (int rep = 0; rep < 8; ++rep) {   // 256 rows x 64 k = 2048 uint4
                const int idx = rep * 256 + t;
                const int n = idx >> 3, c = idx & 7;
                *(uint4*)(sW + n * LDW + c * 8) =
                    *(const uint4*)(Wt + (size_t)n * Mm + zrow0 + h * 64 + c * 8);
            }
            __syncthreads();
            #pragma unroll
            for (int kb = 0; kb < 2; ++kb) {
                const int kof = kb * 32 + quad * 8;
                frag8 ap[4];
                #pragma unroll
                for (int i = 0; i < 4; ++i)
                    ap[i] = *(const frag8*)(
                        sP + (px * 64 + 16 * i + l16) * LDP + h * 64 + kof);
                #pragma unroll
                for (int j = 0; j < 8; ++j) {
                    const frag8 bw = *(const frag8*)(
                        sW + (py * 128 + 16 * j + l16) * LDW + kof);
                    #pragma unroll
                    for (int i = 0; i < 4; ++i)
                        Oa[i][j] = __builtin_amdgcn_mfma_f32_16x16x32_bf16(
                            ap[i], bw, Oa[i][j], 0, 0, 0);
                }
            }
            __syncthreads();   // sW reads done before restage / next-mt staging
        }
    }

    // ---- epilogue: combine 8 M-chunks via fp32 atomics (XCD-local lines) ----
    #pragma unroll
    for (int i = 0; i < 4; ++i) {
        const int xr = row0 + px * 64 + 16 * i + quad * 4;
        #pragma unroll
        for (int j = 0; j < 8; ++j) {
            const int col = py * 128 + 16 * j + l16;
            #pragma unroll
            for (int r = 0; r < 4; ++r)
                atomicAdd(&O[(size_t)(xr + r) * Yd + col], Oa[i][j][r]);
        }
    }
}

// ---- fallback (round-1 fp32 kernel) if workspace is too small ----
constexpr int FBM = 64, FBN = 64, FBK = 64;
constexpr int FMCH = 4, FMCHUNK = Mm / FMCH, FMSTEPS = FMCHUNK / FBN, FDSTEPS = Dd / FBK;
constexpr int FLDA = FBK + 1, FLDSS = FBN + 1;

__global__ __launch_bounds__(256, 3) void laplace_fused_v1(
    const float* __restrict__ X, const float* __restrict__ Z,
    const float* __restrict__ W, float* __restrict__ O)
{
    __shared__ float sX[FBM * FLDA];
    __shared__ float sZ[FBN * FLDA];
    __shared__ float sS[FBM * FLDSS];
    const int t = threadIdx.x, pr = t >> 4, pc = t & 15, sc4 = pc * 4;
    const int row0 = blockIdx.x * FBM, mbase = blockIdx.y * FMCHUNK;
    float o[4][4][4];
    #pragma unroll
    for (int i = 0; i < 4; ++i)
        for (int yb = 0; yb < 4; ++yb)
            for (int j = 0; j < 4; ++j) o[i][yb][j] = 0.0f;
    for (int ms = 0; ms < FMSTEPS; ++ms) {
        const int zrow0 = mbase + ms * FBN;
        float s[4][4];
        #pragma unroll
        for (int i = 0; i < 4; ++i)
            for (int j = 0; j < 4; ++j) s[i][j] = 0.0f;
        for (int kk = 0; kk < FDSTEPS; ++kk) {
            const int k0 = kk * FBK;
            __syncthreads();
            #pragma unroll
            for (int rep = 0; rep < 4; ++rep) {
                const int r = pr + rep * 16;
                const float4 xv = *reinterpret_cast<const float4*>(X + (size_t)(row0 + r) * Dd + k0 + sc4);
                const float4 zv = *reinterpret_cast<const float4*>(Z + (size_t)(zrow0 + r) * Dd + k0 + sc4);
                float* dx = sX + r * FLDA + sc4;
                dx[0] = xv.x; dx[1] = xv.y; dx[2] = xv.z; dx[3] = xv.w;
                float* dz = sZ + r * FLDA + sc4;
                dz[0] = zv.x; dz[1] = zv.y; dz[2] = zv.z; dz[3] = zv.w;
            }
            __syncthreads();
            #pragma unroll 4
            for (int k = 0; k < FBK; ++k) {
                float xr[4], zc[4];
                #pragma unroll
                for (int i = 0; i < 4; ++i) xr[i] = sX[(pr * 4 + i) * FLDA + k];
                #pragma unroll
                for (int j = 0; j < 4; ++j) zc[j] = sZ[(pc * 4 + j) * FLDA + k];
                #pragma unroll
                for (int i = 0; i < 4; ++i)
                    #pragma unroll
                    for (int j = 0; j < 4; ++j) {
                        const float d = xr[i] - zc[j];
                        s[i][j] = fmaf(d, d, s[i][j]);
                    }
            }
        }
        #pragma unroll
        for (int i = 0; i < 4; ++i)
            for (int j = 0; j < 4; ++j)
                sS[(pr * 4 + i) * FLDSS + sc4 + j] = __expf(-sqrtf(s[i][j]) * 0.1f);
        __syncthreads();
        #pragma unroll 2
        for (int c = 0; c < FBN; ++c) {
            float sv[4];
            #pragma unroll
            for (int i = 0; i < 4; ++i) sv[i] = sS[(pr * 4 + i) * FLDSS + c];
            const float* wrow = W + (size_t)(zrow0 + c) * Yd;
            #pragma unroll
            for (int yb = 0; yb < 4; ++yb) {
                const float4 wv = *reinterpret_cast<const float4*>(wrow + yb * 64 + sc4);
                #pragma unroll
                for (int i = 0; i < 4; ++i) {
                    o[i][yb][0] = fmaf(sv[i], wv.x, o[i][yb][0]);
                    o[i][yb][1] = fmaf(sv[i], wv.y, o[i][yb][1]);
                    o[i][yb][2] = fmaf(sv[i], wv.z, o[i][yb][2]);
                    o[i][yb][3] = fmaf(sv[i], wv.w, o[i][yb][3]);
                }
            }
        }
        __syncthreads();
    }
    #pragma unroll
    for (int i = 0; i < 4; ++i) {
        const size_t rbase = (size_t)(row0 + pr * 4 + i) * Yd;
        #pragma unroll
        for (int yb = 0; yb < 4; ++yb)
            for (int j = 0; j < 4; ++j)
                atomicAdd(O + rbase + yb * 64 + sc4 + j, o[i][yb][j]);
    }
}

extern "C" void kernel_launch(void* const* d_in, const int* in_sizes, int n_in,
                              void* d_out, int out_size, void* d_ws, size_t ws_size,
                              hipStream_t stream) {
    const float* X = (const float*)d_in[0];
    const float* Z = (const float*)d_in[1];
    const float* W = (const float*)d_in[2];
    float* O = (float*)d_out;

    hipMemsetAsync(d_out, 0, (size_t)out_size * sizeof(float), stream);

    if (ws_size < WS_NEED) {
        dim3 grid(Nn / FBM, FMCH);
        laplace_fused_v1<<<grid, dim3(256), 0, stream>>>(X, Z, W, O);
        return;
    }

    char* ws = (char*)d_ws;
    ushort* Xb  = (ushort*)(ws + OFF_XB);
    ushort* Zb  = (ushort*)(ws + OFF_ZB);
    ushort* Wt  = (ushort*)(ws + OFF_WT);
    float*  xsq = (float*)(ws + OFF_XSQ);
    float*  zsq = (float*)(ws + OFF_ZSQ);

    cast_norm_xz<<<dim3((Nn + Mm) / 4), dim3(256), 0, stream>>>(X, Z, Xb, Zb, xsq, zsq);
    transpose_w<<<dim3(Mm / 64, Yd / 64), dim3(256), 0, stream>>>(W, Wt);

    laplace_mfma16<<<dim3(Nn / BM, MCH), dim3(256), 0, stream>>>(
        Xb, Zb, Wt, xsq, zsq, O);
}

// Round 6
// 289.745 us; speedup vs baseline: 1.5971x; 1.5571x over previous
//
#include <hip/hip_runtime.h>

// Laplacian-kernel regression, fused flash-style, bf16 MFMA 16x16x32, 4x4
// register blocking in BOTH GEMMs (8 ds_read_b128 per 16 MFMA = 0.5/MFMA).
//   d2 = ||x||^2 + ||z||^2 - 2 X.Z^T ; P = exp(-sqrt(d2)/10) ; out = P @ W
// 512 thr / 8 waves; S-tile BM=128 x BN=256 (wave grid 2x4, 64x64 per wave);
// PV: O = 128x256, wave = 64x64. Grid (64 row-tiles, 4 chunks) = 256 blocks,
// 1 block/CU (124 KB LDS), 8 waves/CU. MCH=4 keeps atomic volume at 32 MB —
// R4/R5's MCH=8 epilogue caused 261 MB HBM write + ~260 MB RMW-fetch (the
// real regression; placement was secondary).
// LDS: sW aliases sX/sZ (phase-disjoint).

using frag8 = __attribute__((ext_vector_type(8))) short;   // 8 bf16 (4 VGPRs)
using f32x4 = __attribute__((ext_vector_type(4))) float;   // 16x16 C/D frag

constexpr int Nn = 8192, Mm = 8192, Dd = 512, Yd = 256;
constexpr int BM = 128, BN = 256, BK = 64;
constexpr int MCH = 4, MPER = Mm / MCH, MT = MPER / BN;    // 4 chunks, 8 tiles
constexpr int LDX = BK + 8;    // 72 bf16 (144 B rows; dword shift 4 -> 2-way)
constexpr int LDP = BN + 8;    // 264
constexpr int LDW = BK + 8;    // 72

// LDS layout (bytes): sX [0,18432) ; sZ [18432,55296) ; sW alias [0,36864);
// sP [55296,122880) ; sXsq [122880,123392) ; sZsq [123392,124416)
constexpr int SMEM_BYTES = 124416;

// workspace layout (bytes)
constexpr size_t OFF_XB  = 0;
constexpr size_t OFF_ZB  = OFF_XB + (size_t)Nn * Dd * 2;
constexpr size_t OFF_WT  = OFF_ZB + (size_t)Mm * Dd * 2;
constexpr size_t OFF_XSQ = OFF_WT + (size_t)Yd * Mm * 2;
constexpr size_t OFF_ZSQ = OFF_XSQ + (size_t)Nn * 4;
constexpr size_t WS_NEED = OFF_ZSQ + (size_t)Mm * 4;       // ~21 MB

__device__ __forceinline__ ushort f2bf(float f) {
    unsigned u = __builtin_bit_cast(unsigned, f);
    u += 0x7FFFu + ((u >> 16) & 1u);
    return (ushort)(u >> 16);
}

// ---- prep 1: bf16 cast + row norms for X and Z in one launch ----
__global__ __launch_bounds__(256) void cast_norm_xz(
    const float* __restrict__ X, const float* __restrict__ Z,
    ushort* __restrict__ Xb, ushort* __restrict__ Zb,
    float* __restrict__ xsq, float* __restrict__ zsq) {
    const int wid = threadIdx.x >> 6, lane = threadIdx.x & 63;
    int row = blockIdx.x * 4 + wid;
    const float* src; ushort* dst; float* nrm;
    if (row < Nn) { src = X; dst = Xb; nrm = xsq; }
    else { row -= Nn; src = Z; dst = Zb; nrm = zsq; }
    const float* s = src + (size_t)row * Dd + lane * 8;
    const float4 a = ((const float4*)s)[0];
    const float4 b = ((const float4*)s)[1];
    uint4 pk;
    pk.x = (unsigned)f2bf(a.x) | ((unsigned)f2bf(a.y) << 16);
    pk.y = (unsigned)f2bf(a.z) | ((unsigned)f2bf(a.w) << 16);
    pk.z = (unsigned)f2bf(b.x) | ((unsigned)f2bf(b.y) << 16);
    pk.w = (unsigned)f2bf(b.z) | ((unsigned)f2bf(b.w) << 16);
    *(uint4*)(dst + (size_t)row * Dd + lane * 8) = pk;
    float sq = a.x*a.x + a.y*a.y + a.z*a.z + a.w*a.w
             + b.x*b.x + b.y*b.y + b.z*b.z + b.w*b.w;
    #pragma unroll
    for (int off = 32; off; off >>= 1) sq += __shfl_xor(sq, off);
    if (lane == 0) nrm[row] = sq;
}

// ---- prep 2: W[8192][256] fp32 -> Wt[256][8192] bf16 ----
__global__ __launch_bounds__(256) void transpose_w(const float* __restrict__ Wf,
                                                   ushort* __restrict__ Wt) {
    __shared__ float tile[64][65];
    const int m0 = blockIdx.x * 64, n0 = blockIdx.y * 64;
    const int t = threadIdx.x;
    #pragma unroll
    for (int rep = 0; rep < 4; ++rep) {
        const int r = rep * 16 + (t >> 4), c4 = (t & 15) * 4;
        const float4 v = *(const float4*)(Wf + (size_t)(m0 + r) * Yd + n0 + c4);
        tile[r][c4] = v.x; tile[r][c4+1] = v.y; tile[r][c4+2] = v.z; tile[r][c4+3] = v.w;
    }
    __syncthreads();
    #pragma unroll
    for (int rep = 0; rep < 4; ++rep) {
        const int n = rep * 16 + (t >> 4), m4 = (t & 15) * 4;
        ushort4 pk;
        pk.x = f2bf(tile[m4+0][n]); pk.y = f2bf(tile[m4+1][n]);
        pk.z = f2bf(tile[m4+2][n]); pk.w = f2bf(tile[m4+3][n]);
        *(ushort4*)(Wt + (size_t)(n0 + n) * Mm + m0 + m4) = pk;
    }
}

// ---- main fused kernel ----
__global__ __launch_bounds__(512, 1) void laplace_mfma16(
    const ushort* __restrict__ Xb, const ushort* __restrict__ Zb,
    const ushort* __restrict__ Wt, const float* __restrict__ xsqg,
    const float* __restrict__ zsqg, float* __restrict__ O)
{
    __shared__ __align__(16) char smem[SMEM_BYTES];
    ushort* sX = (ushort*)smem;                      // 128 x 72
    ushort* sZ = (ushort*)(smem + 18432);            // 256 x 72
    ushort* sW = (ushort*)smem;                      // 256 x 72 (alias, 36.9 KB)
    ushort* sP = (ushort*)(smem + 55296);            // 128 x 264
    float* sXsq = (float*)(smem + 122880);           // 128
    float* sZsq = (float*)(smem + 123392);           // 256

    const int t = threadIdx.x;
    const int wid = t >> 6, lane = t & 63;
    const int l16 = lane & 15, quad = lane >> 4;
    const int wx = wid >> 2, wq = wid & 3;           // wave grid 2x4
    const int row0  = blockIdx.x * BM;               // XCD = blockIdx.x % 8
    const int zbase = blockIdx.y * MPER;

    if (t < 128) sXsq[t] = xsqg[row0 + t];

    f32x4 Oa[4][4];                                  // 64x64 per wave, 64 VGPRs
    #pragma unroll
    for (int i = 0; i < 4; ++i)
        #pragma unroll
        for (int j = 0; j < 4; ++j)
            #pragma unroll
            for (int r = 0; r < 4; ++r) Oa[i][j][r] = 0.0f;

    for (int mt = 0; mt < MT; ++mt) {
        const int zrow0 = zbase + mt * BN;
        if (t < 256) sZsq[t] = zsqg[zrow0 + t];      // visible via kk=0 barrier

        f32x4 S[4][4];
        #pragma unroll
        for (int i = 0; i < 4; ++i)
            #pragma unroll
            for (int j = 0; j < 4; ++j)
                #pragma unroll
                for (int r = 0; r < 4; ++r) S[i][j][r] = 0.0f;

        // ---- QK: S = X_tile[128xD] . Z_tile[256xD]^T, 8 slabs of K=64 ----
        for (int kk = 0; kk < Dd / BK; ++kk) {
            __syncthreads();   // prev consumers done (MFMA reads / sW reads)
            const ushort* xsrc = Xb + (size_t)row0 * Dd + kk * BK;
            const ushort* zsrc = Zb + (size_t)zrow0 * Dd + kk * BK;
            // sX: 128 rows x 8 uint4; sZ: 256 rows x 8 uint4 (3072 total)
            #pragma unroll
            for (int rep = 0; rep < 2; ++rep) {      // X: 1024 uint4
                const int idx = rep * 512 + t;
                const int r = idx >> 3, c = idx & 7;
                *(uint4*)(sX + r * LDX + c * 8) =
                    *(const uint4*)(xsrc + (size_t)r * Dd + c * 8);
            }
            #pragma unroll
            for (int rep = 0; rep < 4; ++rep) {      // Z: 2048 uint4
                const int idx = rep * 512 + t;
                const int r = idx >> 3, c = idx & 7;
                *(uint4*)(sZ + r * LDX + c * 8) =
                    *(const uint4*)(zsrc + (size_t)r * Dd + c * 8);
            }
            __syncthreads();
            #pragma unroll
            for (int ks = 0; ks < 2; ++ks) {
                const int kof = ks * 32 + quad * 8;
                frag8 a[4], b[4];
                #pragma unroll
                for (int i = 0; i < 4; ++i)
                    a[i] = *(const frag8*)(sX + (wx * 64 + 16 * i + l16) * LDX + kof);
                #pragma unroll
                for (int j = 0; j < 4; ++j)
                    b[j] = *(const frag8*)(sZ + (wq * 64 + 16 * j + l16) * LDX + kof);
                #pragma unroll
                for (int i = 0; i < 4; ++i)
                    #pragma unroll
                    for (int j = 0; j < 4; ++j)
                        S[i][j] = __builtin_amdgcn_mfma_f32_16x16x32_bf16(
                            a[i], b[j], S[i][j], 0, 0, 0);
            }
        }

        // ---- transform -> sP[x][z] bf16 (C/D: col=l16, row=quad*4+reg) ----
        #pragma unroll
        for (int i = 0; i < 4; ++i) {
            const int xl = wx * 64 + 16 * i + quad * 4;
            #pragma unroll
            for (int j = 0; j < 4; ++j) {
                const int col = wq * 64 + 16 * j + l16;
                const float zs = sZsq[col];
                #pragma unroll
                for (int r = 0; r < 4; ++r) {
                    const float d2 = fmaxf(sXsq[xl + r] + zs - 2.0f * S[i][j][r], 0.0f);
                    sP[(xl + r) * LDP + col] = f2bf(__expf(-0.1f * __builtin_sqrtf(d2)));
                }
            }
        }
        __syncthreads();   // sP visible; sX/sZ reads done -> sW may overwrite

        // ---- PV: O += P[128x256] . W[256x256], z in 4 slabs of 64 ----
        #pragma unroll
        for (int zs = 0; zs < 4; ++zs) {
            if (zs) __syncthreads();                 // prev sW reads done
            // stage sW[256 y][64 z]: 2048 uint4
            #pragma unroll
            for (int rep = 0; rep < 4; ++rep) {
                const int idx = rep * 512 + t;
                const int n = idx >> 3, c = idx & 7;
                *(uint4*)(sW + n * LDW + c * 8) =
                    *(const uint4*)(Wt + (size_t)n * Mm + zrow0 + zs * 64 + c * 8);
            }
            __syncthreads();
            #pragma unroll
            for (int kb = 0; kb < 2; ++kb) {
                const int kof = kb * 32 + quad * 8;
                frag8 ap[4];
                #pragma unroll
                for (int i = 0; i < 4; ++i)
                    ap[i] = *(const frag8*)(
                        sP + (wx * 64 + 16 * i + l16) * LDP + zs * 64 + kof);
                #pragma unroll
                for (int j = 0; j < 4; ++j) {
                    const frag8 bw = *(const frag8*)(
                        sW + (wq * 64 + 16 * j + l16) * LDW + kof);
                    #pragma unroll
                    for (int i = 0; i < 4; ++i)
                        Oa[i][j] = __builtin_amdgcn_mfma_f32_16x16x32_bf16(
                            ap[i], bw, Oa[i][j], 0, 0, 0);
                }
            }
        }
        // next m-tile's kk=0 barrier protects sW before sX/sZ restage
    }

    // ---- epilogue: combine 4 M-chunks via fp32 atomics (XCD-local lines) ----
    #pragma unroll
    for (int i = 0; i < 4; ++i) {
        const int xr = row0 + wx * 64 + 16 * i + quad * 4;
        #pragma unroll
        for (int j = 0; j < 4; ++j) {
            const int col = wq * 64 + 16 * j + l16;
            #pragma unroll
            for (int r = 0; r < 4; ++r)
                atomicAdd(&O[(size_t)(xr + r) * Yd + col], Oa[i][j][r]);
        }
    }
}

// ---- fallback (round-1 fp32 kernel) if workspace is too small ----
constexpr int FBM = 64, FBN = 64, FBK = 64;
constexpr int FMCH = 4, FMCHUNK = Mm / FMCH, FMSTEPS = FMCHUNK / FBN, FDSTEPS = Dd / FBK;
constexpr int FLDA = FBK + 1, FLDSS = FBN + 1;

__global__ __launch_bounds__(256, 3) void laplace_fused_v1(
    const float* __restrict__ X, const float* __restrict__ Z,
    const float* __restrict__ W, float* __restrict__ O)
{
    __shared__ float sX[FBM * FLDA];
    __shared__ float sZ[FBN * FLDA];
    __shared__ float sS[FBM * FLDSS];
    const int t = threadIdx.x, pr = t >> 4, pc = t & 15, sc4 = pc * 4;
    const int row0 = blockIdx.x * FBM, mbase = blockIdx.y * FMCHUNK;
    float o[4][4][4];
    #pragma unroll
    for (int i = 0; i < 4; ++i)
        for (int yb = 0; yb < 4; ++yb)
            for (int j = 0; j < 4; ++j) o[i][yb][j] = 0.0f;
    for (int ms = 0; ms < FMSTEPS; ++ms) {
        const int zrow0 = mbase + ms * FBN;
        float s[4][4];
        #pragma unroll
        for (int i = 0; i < 4; ++i)
            for (int j = 0; j < 4; ++j) s[i][j] = 0.0f;
        for (int kk = 0; kk < FDSTEPS; ++kk) {
            const int k0 = kk * FBK;
            __syncthreads();
            #pragma unroll
            for (int rep = 0; rep < 4; ++rep) {
                const int r = pr + rep * 16;
                const float4 xv = *reinterpret_cast<const float4*>(X + (size_t)(row0 + r) * Dd + k0 + sc4);
                const float4 zv = *reinterpret_cast<const float4*>(Z + (size_t)(zrow0 + r) * Dd + k0 + sc4);
                float* dx = sX + r * FLDA + sc4;
                dx[0] = xv.x; dx[1] = xv.y; dx[2] = xv.z; dx[3] = xv.w;
                float* dz = sZ + r * FLDA + sc4;
                dz[0] = zv.x; dz[1] = zv.y; dz[2] = zv.z; dz[3] = zv.w;
            }
            __syncthreads();
            #pragma unroll 4
            for (int k = 0; k < FBK; ++k) {
                float xr[4], zc[4];
                #pragma unroll
                for (int i = 0; i < 4; ++i) xr[i] = sX[(pr * 4 + i) * FLDA + k];
                #pragma unroll
                for (int j = 0; j < 4; ++j) zc[j] = sZ[(pc * 4 + j) * FLDA + k];
                #pragma unroll
                for (int i = 0; i < 4; ++i)
                    #pragma unroll
                    for (int j = 0; j < 4; ++j) {
                        const float d = xr[i] - zc[j];
                        s[i][j] = fmaf(d, d, s[i][j]);
                    }
            }
        }
        #pragma unroll
        for (int i = 0; i < 4; ++i)
            for (int j = 0; j < 4; ++j)
                sS[(pr * 4 + i) * FLDSS + sc4 + j] = __expf(-sqrtf(s[i][j]) * 0.1f);
        __syncthreads();
        #pragma unroll 2
        for (int c = 0; c < FBN; ++c) {
            float sv[4];
            #pragma unroll
            for (int i = 0; i < 4; ++i) sv[i] = sS[(pr * 4 + i) * FLDSS + c];
            const float* wrow = W + (size_t)(zrow0 + c) * Yd;
            #pragma unroll
            for (int yb = 0; yb < 4; ++yb) {
                const float4 wv = *reinterpret_cast<const float4*>(wrow + yb * 64 + sc4);
                #pragma unroll
                for (int i = 0; i < 4; ++i) {
                    o[i][yb][0] = fmaf(sv[i], wv.x, o[i][yb][0]);
                    o[i][yb][1] = fmaf(sv[i], wv.y, o[i][yb][1]);
                    o[i][yb][2] = fmaf(sv[i], wv.z, o[i][yb][2]);
                    o[i][yb][3] = fmaf(sv[i], wv.w, o[i][yb][3]);
                }
            }
        }
        __syncthreads();
    }
    #pragma unroll
    for (int i = 0; i < 4; ++i) {
        const size_t rbase = (size_t)(row0 + pr * 4 + i) * Yd;
        #pragma unroll
        for (int yb = 0; yb < 4; ++yb)
            for (int j = 0; j < 4; ++j)
                atomicAdd(O + rbase + yb * 64 + sc4 + j, o[i][yb][j]);
    }
}

extern "C" void kernel_launch(void* const* d_in, const int* in_sizes, int n_in,
                              void* d_out, int out_size, void* d_ws, size_t ws_size,
                              hipStream_t stream) {
    const float* X = (const float*)d_in[0];
    const float* Z = (const float*)d_in[1];
    const float* W = (const float*)d_in[2];
    float* O = (float*)d_out;

    hipMemsetAsync(d_out, 0, (size_t)out_size * sizeof(float), stream);

    if (ws_size < WS_NEED) {
        dim3 grid(Nn / FBM, FMCH);
        laplace_fused_v1<<<grid, dim3(256), 0, stream>>>(X, Z, W, O);
        return;
    }

    char* ws = (char*)d_ws;
    ushort* Xb  = (ushort*)(ws + OFF_XB);
    ushort* Zb  = (ushort*)(ws + OFF_ZB);
    ushort* Wt  = (ushort*)(ws + OFF_WT);
    float*  xsq = (float*)(ws + OFF_XSQ);
    float*  zsq = (float*)(ws + OFF_ZSQ);

    cast_norm_xz<<<dim3((Nn + Mm) / 4), dim3(256), 0, stream>>>(X, Z, Xb, Zb, xsq, zsq);
    transpose_w<<<dim3(Mm / 64, Yd / 64), dim3(256), 0, stream>>>(W, Wt);

    laplace_mfma16<<<dim3(Nn / BM, MCH), dim3(512), 0, stream>>>(
        Xb, Zb, Wt, xsq, zsq, O);
}